// Round 17
// baseline (19.344 us; speedup 1.0000x reference)
//
#include <hip/hip_runtime.h>

#define GX 512
#define NF 32
#define XD 1024

#define CELLB 64                 // f16 cell = 32 feats * 2 B
#define NCELL 33                 // 32 cells + boundary
#define RROWB (NCELL * CELLB)    // 2112 B per row
#define LDSBYTES (3 * RROWB)     // 6336 B: 3 grid rows, raw then G IN PLACE

typedef _Float16 half8 __attribute__((ext_vector_type(8)));
typedef __fp16  fp16x2 __attribute__((ext_vector_type(2)));
typedef float  floatx4 __attribute__((ext_vector_type(4)));

union PkU { fp16x2 h; unsigned u; };
union FragU { half8 h; uint4 u4; fp16x2 p[4]; unsigned u[4]; };

__device__ __forceinline__ unsigned pkrtz(float a, float b) {
    PkU x; x.h = __builtin_amdgcn_cvt_pkrtz(a, b); return x.u;
}
__device__ __forceinline__ fp16x2 sp2(float w) {
    __fp16 h = (__fp16)w; fp16x2 v = {h, h}; return v;
}
__device__ __forceinline__ unsigned relu_pk(unsigned s) {
    unsigned r;
    asm("v_pk_max_f16 %0, %1, 0" : "=v"(r) : "v"(s));
    return r;
}

// MAX-OCCUPANCY variant: 128-thread blocks (2 waves), LDS 6.3 KB, VGPR<=64
// (launch_bounds(128,8)) -> 16 wg x 2 waves = 32 waves/CU, 2x every prior
// round. Block = 4 image rows x 64 cols = 3 grid rows. Wave wl owns grid
// row(s) [wl .. 2wl]: stages raw f16, reads 3 B-frags to regs, overwrites the
// SAME LDS row with G (same-wave in-order DS; duplicate seg writes are
// value-identical). One barrier (cross-wave G row wl+1). Pixel loop = R11
// verbatim.
__global__ __launch_bounds__(128, 8) void t3d_main(
    const float* __restrict__ data,
    const float* __restrict__ W1, const float* __restrict__ b1,
    const float* __restrict__ W2, const float* __restrict__ b2,
    const float* __restrict__ W3, const float* __restrict__ b3,
    float* __restrict__ out)
{
    __shared__ uint4 lds4[LDSBYTES / 16];
    unsigned char* raw = (unsigned char*)lds4;

    const int tid  = threadIdx.x;
    const int wl   = tid >> 6;        // wave 0 or 1
    const int lane = tid & 63;
    const int c = lane & 15, g = lane >> 4;

    // XCD swizzle: 4096 wgs, 8 XCDs, 512 contiguous per XCD (bijective)
    const int bid = blockIdx.x;
    const int wg  = (bid & 7) * 512 + (bid >> 3);
    const int RBb = wg >> 4;          // row-block: image rows 4RBb..4RBb+3
    const int cbk = wg & 15;          // 64-pixel column block
    const int XB  = 32 * cbk;         // first grid cell
    const int YB  = 2 * RBb;          // first grid row

    // ---- wave-private staging of owned rows (R16-verified formulas) --------
    const int cl8 = lane >> 3, fl = lane & 7;    // 8 lanes per cell
#pragma unroll
    for (int r = wl; r <= 2 * wl; ++r) {
        const int y = min(YB + r, GX - 1);
        const float* rowp = data + (size_t)y * (GX * NF);
        floatx4 v[4];
#pragma unroll
        for (int k = 0; k < 4; ++k)
            v[k] = *(const floatx4*)(rowp + (XB + 8 * k + cl8) * NF + 4 * fl);
        floatx4 vb;
        if (lane < 8)
            vb = *(const floatx4*)(rowp + min(XB + 32, GX - 1) * NF + 4 * lane);
        unsigned char* pr = raw + r * RROWB;
#pragma unroll
        for (int k = 0; k < 4; ++k) {
            const int cell = 8 * k + cl8;
            uint2 u = { pkrtz(v[k][0], v[k][1]), pkrtz(v[k][2], v[k][3]) };
            *(uint2*)(pr + cell * CELLB
                      + (((fl >> 1) ^ ((cell >> 1) & 3)) << 4) + ((fl & 1) << 3)) = u;
        }
        if (lane < 8) {
            uint2 u = { pkrtz(vb[0], vb[1]), pkrtz(vb[2], vb[3]) };
            *(uint2*)(pr + 32 * CELLB + ((lane >> 1) << 4) + ((lane & 1) << 3)) = u;
        }
    }

    // ---- layer-1 weight fragments (standard mapping, R11 verbatim) ---------
    {
        FragU aw1[2]; floatx4 bia1[2];
#pragma unroll
        for (int jt = 0; jt < 2; ++jt) {
#pragma unroll
            for (int w = 0; w < 4; ++w)
                aw1[jt].u[w] = pkrtz(W1[(8*g+2*w)*NF + 16*jt + c], W1[(8*g+2*w+1)*NF + 16*jt + c]);
            bia1[jt] = ((const floatx4*)b1)[4*jt + g];
        }

        // ---- in-place G for owned rows: read 3 B-frags FIRST, then write ---
#pragma unroll
        for (int r = wl; r <= 2 * wl; ++r) {
            unsigned char* pr = raw + r * RROWB;
            const int c0 = c, c1 = 16 + c, c2 = 17 + c;
            FragU B0, B1, B2;
            B0.u4 = *(const uint4*)(pr + c0 * CELLB + ((g ^ ((c0 >> 1) & 3)) << 4));
            B1.u4 = *(const uint4*)(pr + c1 * CELLB + ((g ^ ((c1 >> 1) & 3)) << 4));
            B2.u4 = *(const uint4*)(pr + c2 * CELLB + ((g ^ ((c2 >> 1) & 3)) << 4));
            floatx4 d00 = __builtin_amdgcn_mfma_f32_16x16x32_f16(aw1[0].h, B0.h, bia1[0], 0, 0, 0);
            floatx4 d01 = __builtin_amdgcn_mfma_f32_16x16x32_f16(aw1[1].h, B0.h, bia1[1], 0, 0, 0);
            floatx4 d10 = __builtin_amdgcn_mfma_f32_16x16x32_f16(aw1[0].h, B1.h, bia1[0], 0, 0, 0);
            floatx4 d11 = __builtin_amdgcn_mfma_f32_16x16x32_f16(aw1[1].h, B1.h, bia1[1], 0, 0, 0);
            floatx4 d20 = __builtin_amdgcn_mfma_f32_16x16x32_f16(aw1[0].h, B2.h, bia1[0], 0, 0, 0);
            floatx4 d21 = __builtin_amdgcn_mfma_f32_16x16x32_f16(aw1[1].h, B2.h, bia1[1], 0, 0, 0);
#define GW(cell, d0, d1) {                                                        \
            const int sg = ((cell) >> 1) & 3;                                     \
            unsigned char* gc = pr + (cell) * CELLB + ((g & 1) << 3);             \
            uint2 u0 = { pkrtz((d0)[0], (d0)[1]), pkrtz((d0)[2], (d0)[3]) };      \
            uint2 u1 = { pkrtz((d1)[0], (d1)[1]), pkrtz((d1)[2], (d1)[3]) };      \
            *(uint2*)(gc + ((((g >> 1)    ) ^ sg) << 4)) = u0;                    \
            *(uint2*)(gc + ((((g >> 1) + 2) ^ sg) << 4)) = u1; }
            GW(c0, d00, d01)
            GW(c1, d10, d11)
            GW(c2, d20, d21)
#undef GW
        }
    }

    __syncthreads();   // cross-wave: wave wl reads G row wl+1

    // ---- layer-2/3 weight fragments (loaded after barrier; aw1 is dead) ----
    FragU aw2[2]; floatx4 bia2[2], w3f[2];
#pragma unroll
    for (int jt = 0; jt < 2; ++jt) {
#pragma unroll
        for (int w = 0; w < 4; ++w)
            aw2[jt].u[w] = pkrtz(W2[(8*g+2*w)*NF + 16*jt + c], W2[(8*g+2*w+1)*NF + 16*jt + c]);
        bia2[jt] = ((const floatx4*)b2)[4*jt + g];
        w3f[jt]  = ((const floatx4*)W3)[4*jt + g];
    }

    // ---- pixel loop (R11 verbatim): wave = image rows {4RBb+2wl, +1} -------
    const float w0p = (c & 1) ? 0.75f : 0.25f;
    const float m0  = 1.0f - w0p;
    const fp16x2 WA[2] = { sp2(m0  * 0.75f), sp2(m0  * 0.25f) };
    const fp16x2 WB[2] = { sp2(w0p * 0.75f), sp2(w0p * 0.25f) };
    const fp16x2 WC[2] = { sp2(m0  * 0.25f), sp2(m0  * 0.75f) };
    const fp16x2 WD[2] = { sp2(w0p * 0.25f), sp2(w0p * 0.75f) };

    unsigned char* Gt = raw + wl * RROWB;        // grid row wl   (y0)
    unsigned char* Gm = raw + (wl + 1) * RROWB;  // grid row wl+1 (y1)

    float ss[8];
#pragma unroll
    for (int ct = 0; ct < 4; ++ct) {
        const int o0 = 8 * ct + (c >> 1);
        const int o1 = o0 + 1;                   // boundary cell pre-clamped
        const int a0 = o0 * CELLB + ((g ^ ((o0 >> 1) & 3)) << 4);
        const int a1 = o1 * CELLB + ((g ^ ((o1 >> 1) & 3)) << 4);
        FragU cT0, cT1, cB0, cB1;
        cT0.u4 = *(const uint4*)(Gt + a0);
        cT1.u4 = *(const uint4*)(Gt + a1);
        cB0.u4 = *(const uint4*)(Gm + a0);
        cB1.u4 = *(const uint4*)(Gm + a1);
#pragma unroll
        for (int par = 0; par < 2; ++par) {
            FragU f;
#pragma unroll
            for (int w = 0; w < 4; ++w) {
                fp16x2 t0 = cT0.p[w] * WA[par] + cT1.p[w] * WB[par];
                fp16x2 t1 = cB0.p[w] * WC[par] + cB1.p[w] * WD[par];
                PkU s; s.h = t0 + t1;
                f.u[w] = relu_pk(s.u);           // h1 = relu(interp(G))
            }
            floatx4 e0 = __builtin_amdgcn_mfma_f32_16x16x32_f16(aw2[0].h, f.h, bia2[0], 0, 0, 0);
            floatx4 e1 = __builtin_amdgcn_mfma_f32_16x16x32_f16(aw2[1].h, f.h, bia2[1], 0, 0, 0);
            float t = 0.0f;
#pragma unroll
            for (int r = 0; r < 4; ++r) {
                t = fmaf(fmaxf(e0[r], 0.0f), w3f[0][r], t);
                t = fmaf(fmaxf(e1[r], 0.0f), w3f[1][r], t);
            }
            ss[par * 4 + ct] = t;
        }
    }

    // ---- batched reduction over g-groups (verified pattern) ----------------
    const bool lo = (lane < 32);
    float tt[4];
#pragma unroll
    for (int k = 0; k < 4; ++k) {
        const float x  = lo ? ss[4 + k] : ss[k];
        const float rv = __shfl_xor(x, 32, 64);
        tt[k] = (lo ? ss[k] : ss[4 + k]) + rv;
    }
    const bool go = (g & 1);
    const float u0 = go ? tt[0] : tt[2];
    const float r0 = __shfl_xor(u0, 16, 64);
    const float fin0 = (go ? tt[2] : tt[0]) + r0;
    const float u1 = go ? tt[1] : tt[3];
    const float r1 = __shfl_xor(u1, 16, 64);
    const float fin1 = (go ? tt[3] : tt[1]) + r1;

    // lane (g,c): row 4RBb+2wl+(g>>1), cols 64cbk+32(g&1)+c and +16
    const float b3v = b3[0];
    const int orow = 4 * RBb + 2 * wl + (g >> 1);
    const int ocol = 64 * cbk + 32 * (g & 1) + c;
    out[(size_t)orow * XD + ocol]      = fin0 + b3v;
    out[(size_t)orow * XD + ocol + 16] = fin1 + b3v;
}

extern "C" void kernel_launch(void* const* d_in, const int* in_sizes, int n_in,
                              void* d_out, int out_size, void* d_ws, size_t ws_size,
                              hipStream_t stream) {
    // inputs: z, data, W1, b1, W2, b2, W3, b3, x0, y0, x1, y1, lerp_weights
    const float* data = (const float*)d_in[1];
    const float* W1   = (const float*)d_in[2];
    const float* b1   = (const float*)d_in[3];
    const float* W2   = (const float*)d_in[4];
    const float* b2   = (const float*)d_in[5];
    const float* W3   = (const float*)d_in[6];
    const float* b3   = (const float*)d_in[7];
    float* out = (float*)d_out;
    (void)d_ws; (void)ws_size;

    const int blocks = 4096;   // 256 row-blocks x 16 col-blocks, 128 thr each
    hipLaunchKernelGGL(t3d_main, dim3(blocks), dim3(128), 0, stream,
                       data, W1, b1, W2, b2, W3, b3, out);
}

// Round 18
// 16.401 us; speedup vs baseline: 1.1794x; 1.1794x over previous
//
#include <hip/hip_runtime.h>

#define GX 512
#define NF 32
#define XD 1024

#define CELLB 64                 // f16 cell = 32 feats * 2 B
#define NCELL 33                 // 32 cells + boundary
#define RROWB (NCELL * CELLB)    // 2112 B per staged row
#define RAWB  (5 * RROWB)        // 10560 B raw corners (5 grid rows) -- ONLY LDS

typedef _Float16 half8 __attribute__((ext_vector_type(8)));
typedef __fp16  fp16x2 __attribute__((ext_vector_type(2)));
typedef float  floatx4 __attribute__((ext_vector_type(4)));

union PkU { fp16x2 h; unsigned u; };
union FragU { half8 h; uint4 u4; fp16x2 p[4]; unsigned u[4]; };

__device__ __forceinline__ unsigned pkrtz(float a, float b) {
    PkU x; x.h = __builtin_amdgcn_cvt_pkrtz(a, b); return x.u;
}
__device__ __forceinline__ fp16x2 sp2(float w) {
    __fp16 h = (__fp16)w; fp16x2 v = {h, h}; return v;
}
__device__ __forceinline__ unsigned relu_pk(unsigned s) {
    unsigned r;
    asm("v_pk_max_f16 %0, %1, 0" : "=v"(r) : "v"(s));
    return r;
}

// R15 structure (best: 16.97) + two work cuts:
// (1) STRIP SCHEDULING: each XCD owns a 64-col strip walked down the rows ->
//     consecutive blocks share a grid row via that XCD's L2 -> HBM ratio ~1.03
//     (was ~1.3). Bijective: cbk = 2*xcd + (idx>>7), RB = idx & 127.
// (2) f16 PACKED INTERP on register-G: pack G quads to fp16x2 once (32 pkrtz),
//     interp with v_pk_fma_f16 + compile-time splat weights (saves ~130 VALU
//     per wave vs f32 interp). pi-permuted k-slots preserved (R15).
__global__ __launch_bounds__(256, 4) void t3d_main(
    const float* __restrict__ data,
    const float* __restrict__ W1, const float* __restrict__ b1,
    const float* __restrict__ W2, const float* __restrict__ b2,
    const float* __restrict__ W3, const float* __restrict__ b3,
    float* __restrict__ out)
{
    __shared__ uint4 lds4[RAWB / 16];
    unsigned char* raw = (unsigned char*)lds4;

    const int tid  = threadIdx.x;
    const int wid  = tid >> 6;
    const int lane = tid & 63;
    const int c = lane & 15, g = lane >> 4;

    // strip scheduling: XCD (bid&7) owns columns [64*cbk, 64*cbk+64)
    const int bid = blockIdx.x;
    const int xcd = bid & 7;
    const int idx = bid >> 3;               // 0..255 within XCD
    const int cbk = 2 * xcd + (idx >> 7);   // column block 0..15
    const int RB  = idx & 127;              // row-block 0..127 (walks down strip)
    const int XB  = 32 * cbk;               // first grid cell
    const int YB  = 4 * RB;                 // first grid row

    // ---- cooperative staging: 5 grid rows x 33 cells, f32 -> f16 (R11) -----
    const int cl = tid >> 3, fl = tid & 7;   // 8 lanes per cell, 32 cells
#pragma unroll
    for (int rr = 0; rr < 5; ++rr) {
        const int y = min(YB + rr, GX - 1);
        const float4 v = *(const float4*)(data + (size_t)y * (GX * NF) + (XB + cl) * NF + 4 * fl);
        uint2 u = { pkrtz(v.x, v.y), pkrtz(v.z, v.w) };
        *(uint2*)(raw + rr * RROWB + cl * CELLB
                  + (((fl >> 1) ^ ((cl >> 1) & 3)) << 4) + ((fl & 1) << 3)) = u;
    }
    if (tid < 40) {   // boundary cell 32 (clamped at grid edge)
        const int rr = tid >> 3, L = tid & 7;
        const int y = min(YB + rr, GX - 1);
        const int col = min(XB + 32, GX - 1);
        const float4 v = *(const float4*)(data + (size_t)y * (GX * NF) + col * NF + 4 * L);
        uint2 u = { pkrtz(v.x, v.y), pkrtz(v.z, v.w) };
        *(uint2*)(raw + rr * RROWB + 32 * CELLB + ((L >> 1) << 4) + ((L & 1) << 3)) = u;
    }

    // ---- weight fragments ---------------------------------------------------
    // aw1: standard k-mapping. aw2: PI-PERMUTED k-slots (R15 verbatim).
    FragU aw1[2], aw2[2]; floatx4 bia1[2], bia2[2], w3f[2];
#pragma unroll
    for (int jt = 0; jt < 2; ++jt) {
#pragma unroll
        for (int w = 0; w < 4; ++w)
            aw1[jt].u[w] = pkrtz(W1[(8*g+2*w)*NF + 16*jt + c], W1[(8*g+2*w+1)*NF + 16*jt + c]);
        aw2[jt].u[0] = pkrtz(W2[(4*g+0)*NF + 16*jt + c],  W2[(4*g+1)*NF + 16*jt + c]);
        aw2[jt].u[1] = pkrtz(W2[(4*g+2)*NF + 16*jt + c],  W2[(4*g+3)*NF + 16*jt + c]);
        aw2[jt].u[2] = pkrtz(W2[(16+4*g+0)*NF + 16*jt + c], W2[(16+4*g+1)*NF + 16*jt + c]);
        aw2[jt].u[3] = pkrtz(W2[(16+4*g+2)*NF + 16*jt + c], W2[(16+4*g+3)*NF + 16*jt + c]);
        bia1[jt] = ((const floatx4*)b1)[4*jt + g];
        bia2[jt] = ((const floatx4*)b2)[4*jt + g];
        w3f[jt]  = ((const floatx4*)W3)[4*jt + g];
    }

    __syncthreads();   // staging is cross-wave; only barrier

#define RD(rr, cell) (*(const uint4*)(raw + (rr) * RROWB + (cell) * CELLB \
                      + ((g ^ (((cell) >> 1) & 3)) << 4)))

    float ss[8];
    // wave = image rows {2wid, 2wid+1}; grid rows wid (T), wid+1 (B)
#pragma unroll
    for (int s = 0; s < 2; ++s) {
        const int c0 = 16 * s + c;
        FragU Bat, Bst, Bab, Bsb;
        Bat.u4 = RD(wid,     c0);      // aligned, top row
        Bst.u4 = RD(wid,     c0 + 1);  // shifted (x1), top
        Bab.u4 = RD(wid + 1, c0);      // aligned, bottom
        Bsb.u4 = RD(wid + 1, c0 + 1);  // shifted, bottom
        floatx4 GTA0 = __builtin_amdgcn_mfma_f32_16x16x32_f16(aw1[0].h, Bat.h, bia1[0], 0, 0, 0);
        floatx4 GTA1 = __builtin_amdgcn_mfma_f32_16x16x32_f16(aw1[1].h, Bat.h, bia1[1], 0, 0, 0);
        floatx4 GTS0 = __builtin_amdgcn_mfma_f32_16x16x32_f16(aw1[0].h, Bst.h, bia1[0], 0, 0, 0);
        floatx4 GTS1 = __builtin_amdgcn_mfma_f32_16x16x32_f16(aw1[1].h, Bst.h, bia1[1], 0, 0, 0);
        floatx4 GBA0 = __builtin_amdgcn_mfma_f32_16x16x32_f16(aw1[0].h, Bab.h, bia1[0], 0, 0, 0);
        floatx4 GBA1 = __builtin_amdgcn_mfma_f32_16x16x32_f16(aw1[1].h, Bab.h, bia1[1], 0, 0, 0);
        floatx4 GBS0 = __builtin_amdgcn_mfma_f32_16x16x32_f16(aw1[0].h, Bsb.h, bia1[0], 0, 0, 0);
        floatx4 GBS1 = __builtin_amdgcn_mfma_f32_16x16x32_f16(aw1[1].h, Bsb.h, bia1[1], 0, 0, 0);

        // pack G to f16 once per seg (k-slot order: u[0..1]=jt0 quads, u[2..3]=jt1)
        FragU At, St, Ab, Sb;
        At.u[0] = pkrtz(GTA0[0], GTA0[1]); At.u[1] = pkrtz(GTA0[2], GTA0[3]);
        At.u[2] = pkrtz(GTA1[0], GTA1[1]); At.u[3] = pkrtz(GTA1[2], GTA1[3]);
        St.u[0] = pkrtz(GTS0[0], GTS0[1]); St.u[1] = pkrtz(GTS0[2], GTS0[3]);
        St.u[2] = pkrtz(GTS1[0], GTS1[1]); St.u[3] = pkrtz(GTS1[2], GTS1[3]);
        Ab.u[0] = pkrtz(GBA0[0], GBA0[1]); Ab.u[1] = pkrtz(GBA0[2], GBA0[3]);
        Ab.u[2] = pkrtz(GBA1[0], GBA1[1]); Ab.u[3] = pkrtz(GBA1[2], GBA1[3]);
        Sb.u[0] = pkrtz(GBS0[0], GBS0[1]); Sb.u[1] = pkrtz(GBS0[2], GBS0[3]);
        Sb.u[2] = pkrtz(GBS1[0], GBS1[1]); Sb.u[3] = pkrtz(GBS1[2], GBS1[3]);

#pragma unroll
        for (int rr = 0; rr < 2; ++rr) {       // image-row parity (y lerp)
#pragma unroll
            for (int tp = 0; tp < 2; ++tp) {   // column parity (x lerp)
                // compile-time corner weights (exact in f16)
                const float w0v = tp ? 0.75f : 0.25f;
                const float w1v = rr ? 0.75f : 0.25f;
                const fp16x2 cWA = sp2((1.0f - w0v) * (1.0f - w1v));
                const fp16x2 cWB = sp2(w0v * (1.0f - w1v));
                const fp16x2 cWC = sp2((1.0f - w0v) * w1v);
                const fp16x2 cWD = sp2(w0v * w1v);
                FragU f;
#pragma unroll
                for (int w = 0; w < 4; ++w) {
                    fp16x2 t0 = At.p[w] * cWA + St.p[w] * cWB;
                    fp16x2 t1 = Ab.p[w] * cWC + Sb.p[w] * cWD;
                    PkU sv; sv.h = t0 + t1;
                    f.u[w] = relu_pk(sv.u);
                }
                floatx4 e0 = __builtin_amdgcn_mfma_f32_16x16x32_f16(aw2[0].h, f.h, bia2[0], 0, 0, 0);
                floatx4 e1 = __builtin_amdgcn_mfma_f32_16x16x32_f16(aw2[1].h, f.h, bia2[1], 0, 0, 0);
                float t = 0.0f;
#pragma unroll
                for (int r = 0; r < 4; ++r) {
                    t = fmaf(fmaxf(e0[r], 0.0f), w3f[0][r], t);
                    t = fmaf(fmaxf(e1[r], 0.0f), w3f[1][r], t);
                }
                ss[(rr << 2) + (s << 1) + tp] = t;
            }
        }
    }
#undef RD

    // ---- batched reduction over g-groups (verified pattern) ----------------
    const bool lo = (lane < 32);
    float tt[4];
#pragma unroll
    for (int k = 0; k < 4; ++k) {
        const float x  = lo ? ss[4 + k] : ss[k];
        const float rv = __shfl_xor(x, 32, 64);
        tt[k] = (lo ? ss[k] : ss[4 + k]) + rv;
    }
    const bool go = (g & 1);
    const float u0 = go ? tt[0] : tt[2];
    const float r0 = __shfl_xor(u0, 16, 64);
    const float fin0 = (go ? tt[2] : tt[0]) + r0;
    const float u1 = go ? tt[1] : tt[3];
    const float r1 = __shfl_xor(u1, 16, 64);
    const float fin1 = (go ? tt[3] : tt[1]) + r1;

    // lane (g,c): slots (2g,2g+1) = (rr=g>>1, s=g&1, tp=0/1)
    // -> row 2wid+(g>>1), cols 32(g&1)+2c, +2c+1 (contiguous float2)
    const float b3v = b3[0];
    const int orow = 8 * RB + 2 * wid + (g >> 1);
    const int ocol = 64 * cbk + 32 * (g & 1) + 2 * c;
    float2 o2 = { fin0 + b3v, fin1 + b3v };
    *(float2*)(out + (size_t)orow * XD + ocol) = o2;
}

extern "C" void kernel_launch(void* const* d_in, const int* in_sizes, int n_in,
                              void* d_out, int out_size, void* d_ws, size_t ws_size,
                              hipStream_t stream) {
    // inputs: z, data, W1, b1, W2, b2, W3, b3, x0, y0, x1, y1, lerp_weights
    const float* data = (const float*)d_in[1];
    const float* W1   = (const float*)d_in[2];
    const float* b1   = (const float*)d_in[3];
    const float* W2   = (const float*)d_in[4];
    const float* b2   = (const float*)d_in[5];
    const float* W3   = (const float*)d_in[6];
    const float* b3   = (const float*)d_in[7];
    float* out = (float*)d_out;
    (void)d_ws; (void)ws_size;

    const int blocks = 2048;   // 8 XCD-strips x 2 col-blocks x 128 row-blocks
    hipLaunchKernelGGL(t3d_main, dim3(blocks), dim3(256), 0, stream,
                       data, W1, b1, W2, b2, W3, b3, out);
}